// Round 7
// baseline (919.521 us; speedup 1.0000x reference)
//
#include <hip/hip_runtime.h>

typedef unsigned short u16;
typedef unsigned int u32;
typedef __attribute__((ext_vector_type(8))) short bf16x8;
typedef __attribute__((ext_vector_type(4))) float f32x4;

#define SB 16
#define SS 2048
#define SD 256
#define CC 16            // chunk length
#define NCH (SS / CC)    // 128 chunks
#define KAPPA 4.8828125e-6f   // 0.01 * 2/(16*256)
#define RP 24            // u16 pitch of transposed 16x16 publish tiles
#define SLOT 65536       // elements per [256,256] transfer slot

__device__ __forceinline__ u16 f2bf(float f) {
  u32 u = __float_as_uint(f);
  u = (u + 0x7FFFu + ((u >> 16) & 1u)) >> 16;
  return (u16)u;
}
__device__ __forceinline__ float bf2f(u16 u) { return __uint_as_float((u32)u << 16); }

__device__ __forceinline__ bf16x8 ldfrag(const u16* p) {
  union { uint4 u; bf16x8 f; } cv;
  cv.u = *(const uint4*)p;
  return cv.f;
}
__device__ __forceinline__ bf16x8 asfrag(uint4 q) {
  union { uint4 u; bf16x8 f; } cv;
  cv.u = q;
  return cv.f;
}
__device__ __forceinline__ f32x4 mfma16(bf16x8 a, bf16x8 b, f32x4 c) {
  return __builtin_amdgcn_mfma_f32_16x16x32_bf16(a, b, c, 0, 0, 0);
}

// ---------------- prep: train/state (bf16 [t][b][d]) + trainT ([t][d][b]) ----
__global__ __launch_bounds__(256) void prep_kernel(
    const float* __restrict__ x, const float* __restrict__ noise,
    const float* __restrict__ a1,
    u16* __restrict__ train, u16* __restrict__ state, u16* __restrict__ trainT) {
  size_t i4 = (size_t)blockIdx.x * 256 + threadIdx.x;
  size_t base = i4 * 4;
  int d = (int)(base & 255);
  int t = (int)((base >> 8) & 2047);
  int b = (int)(base >> 19);
  float4 xv = *(const float4*)(x + base);
  float4 nv = *(const float4*)(noise + base);
  float4 av = *(const float4*)(a1 + d);
  float m0 = tanhf(av.x * xv.x);
  float m1 = tanhf(av.y * xv.y);
  float m2 = tanhf(av.z * xv.z);
  float m3 = tanhf(av.w * xv.w);
  size_t dst = ((size_t)t * SB + b) * SD + d;
  ushort4 tr, st;
  tr.x = f2bf(m0 + nv.x); tr.y = f2bf(m1 + nv.y);
  tr.z = f2bf(m2 + nv.z); tr.w = f2bf(m3 + nv.w);
  st.x = f2bf(m0); st.y = f2bf(m1); st.z = f2bf(m2); st.w = f2bf(m3);
  *(ushort4*)(train + dst) = tr;
  *(ushort4*)(state + dst) = st;
  size_t tb = ((size_t)t * SD + d) * SB + b;   // trainT[t][d][b]
  trainT[tb + 0 * SB] = tr.x;
  trainT[tb + 1 * SB] = tr.y;
  trainT[tb + 2 * SB] = tr.z;
  trainT[tb + 3 * SB] = tr.w;
}

// ---------------- fused: gram2 (blocks 0..2047) || ff' (blocks 2048..4095) --
__global__ __launch_bounds__(256) void gram2ff_kernel(
    const u16* __restrict__ tr, const u16* __restrict__ st,
    u16* __restrict__ AG, u16* __restrict__ LbG,
    const float* __restrict__ x, const float* __restrict__ a2,
    const float* __restrict__ Wp, const float* __restrict__ ffa,
    const float* __restrict__ ffb, const float* __restrict__ ffg_,
    const float* __restrict__ ffe_, float* __restrict__ out) {
  __shared__ float As[32][68];
  __shared__ float Bs[32][68];
  const int tid = threadIdx.x;

  if (blockIdx.x < 2048) {
    const int cb = blockIdx.x;        // c*16 + t
    const int c = cb >> 4, t = cb & 15;
    const int lane = tid & 63, wv = tid >> 6;
    const int lr = lane & 15, lq = lane >> 4;
    const size_t Tt = (size_t)cb;
    bf16x8 trF[8], stF[8];
#pragma unroll
    for (int k = 0; k < 8; ++k) {
      trF[k] = ldfrag(tr + (Tt * 16 + lr) * 256 + k * 32 + lq * 8);
      stF[k] = ldfrag(st + (Tt * 16 + lr) * 256 + k * 32 + lq * 8);
    }
    for (int ii = 0; ii < 2; ++ii) {
      const int sp = wv + ii * 4;
      u16* dA = AG + ((size_t)cb * 8 + sp) * 512;
      u16* dL = LbG + ((size_t)cb * 8 + sp) * 512;
#pragma unroll
      for (int h = 0; h < 2; ++h) {
        const int s = 2 * sp + h;
        f32x4 accA = {0.f, 0.f, 0.f, 0.f}, accL = {0.f, 0.f, 0.f, 0.f};
        if (s <= t) {
          const u16* bsrc = tr + ((size_t)(c * 16 + s) * 16 + lr) * 256 + lq * 8;
#pragma unroll
          for (int k = 0; k < 8; ++k) {
            bf16x8 bk = ldfrag(bsrc + k * 32);
            if (s < t) accA = mfma16(trF[k], bk, accA);
            accL = mfma16(stF[k], bk, accL);
          }
        }
#pragma unroll
        for (int r = 0; r < 4; ++r) {
          int idx = (lq * 4 + r) * 32 + h * 16 + lr;
          dA[idx] = (s < t) ? f2bf(accA[r]) : (u16)0;
          dL[idx] = (s <= t) ? f2bf(accL[r]) : (u16)0;
        }
      }
    }
    return;
  }

  // ---------------- ff' body: out = u .* (v @ Wp^T)  (no prev add) --------
  const int fb = blockIdx.x - 2048;
  const int gm0 = (fb >> 2) * 64;
  const int gn0 = (fb & 3) * 64;
  const int tm = tid & 15, tn = tid >> 4;
  const int lr = tid & 63;
  const int lq = tid >> 6;
  float acc[4][4];
#pragma unroll
  for (int i = 0; i < 4; i++)
#pragma unroll
    for (int j = 0; j < 4; j++) acc[i][j] = 0.f;

  for (int k0 = 0; k0 < 256; k0 += 32) {
    {
      const float* xp = x + (size_t)(gm0 + lr) * 256 + k0 + lq * 8;
      float4 v0 = *(const float4*)(xp);
      float4 v1 = *(const float4*)(xp + 4);
      const float* ap = a2 + k0 + lq * 8;
      float4 a0 = *(const float4*)(ap);
      float4 a1v = *(const float4*)(ap + 4);
      As[lq * 8 + 0][lr] = tanhf(a0.x * v0.x);
      As[lq * 8 + 1][lr] = tanhf(a0.y * v0.y);
      As[lq * 8 + 2][lr] = tanhf(a0.z * v0.z);
      As[lq * 8 + 3][lr] = tanhf(a0.w * v0.w);
      As[lq * 8 + 4][lr] = tanhf(a1v.x * v1.x);
      As[lq * 8 + 5][lr] = tanhf(a1v.y * v1.y);
      As[lq * 8 + 6][lr] = tanhf(a1v.z * v1.z);
      As[lq * 8 + 7][lr] = tanhf(a1v.w * v1.w);
      const float* wp = Wp + (size_t)(gn0 + lr) * 256 + k0 + lq * 8;
      float4 w0 = *(const float4*)(wp);
      float4 w1 = *(const float4*)(wp + 4);
      Bs[lq * 8 + 0][lr] = w0.x; Bs[lq * 8 + 1][lr] = w0.y;
      Bs[lq * 8 + 2][lr] = w0.z; Bs[lq * 8 + 3][lr] = w0.w;
      Bs[lq * 8 + 4][lr] = w1.x; Bs[lq * 8 + 5][lr] = w1.y;
      Bs[lq * 8 + 6][lr] = w1.z; Bs[lq * 8 + 7][lr] = w1.w;
    }
    __syncthreads();
#pragma unroll
    for (int k = 0; k < 32; ++k) {
      float4 av4 = *(const float4*)&As[k][tm * 4];
      float4 bv4 = *(const float4*)&Bs[k][tn * 4];
      float a[4] = {av4.x, av4.y, av4.z, av4.w};
      float b[4] = {bv4.x, bv4.y, bv4.z, bv4.w};
#pragma unroll
      for (int i = 0; i < 4; i++)
#pragma unroll
        for (int j = 0; j < 4; j++) acc[i][j] += a[i] * b[j];
    }
    __syncthreads();
  }
  const float ga = ffg_[0], et = ffe_[0];
#pragma unroll
  for (int ii = 0; ii < 4; ++ii) {
    int row = gm0 + tm * 4 + ii;
    int col = gn0 + tn * 4;
    float4 xv = *(const float4*)(x + (size_t)row * 256 + col);
    float4 fa = *(const float4*)(ffa + col);
    float4 fb4 = *(const float4*)(ffb + col);
    float4 a2v = *(const float4*)(a2 + col);
    float xs[4] = {xv.x, xv.y, xv.z, xv.w};
    float fas[4] = {fa.x, fa.y, fa.z, fa.w};
    float fbs[4] = {fb4.x, fb4.y, fb4.z, fb4.w};
    float a2s[4] = {a2v.x, a2v.y, a2v.z, a2v.w};
    float res[4];
#pragma unroll
    for (int j = 0; j < 4; ++j) {
      float v = tanhf(a2s[j] * xs[j]);
      float z = fas[j] * v;
      float gelu = 0.5f * z * (1.0f + erff(z * 0.70710678118654752f));
      float u = ga * gelu + et * sinf(fbs[j] * v);
      res[j] = u * acc[ii][j];
    }
    float4 o; o.x = res[0]; o.y = res[1]; o.z = res[2]; o.w = res[3];
    *(float4*)(out + (size_t)row * 256 + col) = o;
  }
}

// ---------------- phase A: per-chunk transfer (Dt, Db both orientations) ---
// D_c = -k*Sum_t Ytil_t^T X_t, Ytil = X - k*(A@X);  Q_c = +k*Sum_t Ztil_t^T X_t.
// Grid dim3(16,128): blockIdx.x = d1b (D-row block), blockIdx.y = c.
__global__ __launch_bounds__(512) void phaseA_kernel(
    const u16* __restrict__ tr, const u16* __restrict__ st,
    const u16* __restrict__ trT, const u16* __restrict__ AG,
    u16* __restrict__ Dt, u16* __restrict__ Db, u16* __restrict__ Qb) {
  __shared__ u16 StT[CC][16 * RP];
  __shared__ u16 YtL[CC][16 * RP];
  __shared__ u16 ZtL[CC][16 * RP];
  const int tid = threadIdx.x;
  const int lane = tid & 63;
  const int w = tid >> 6;
  const int d1b = blockIdx.x;
  const int c = blockIdx.y;
  const int lr = lane & 15;
  const int lq = lane >> 4;

  uint4 agR[2][8];
#pragma unroll
  for (int u = 0; u < 2; ++u) {
    const u16* ag = AG + ((size_t)(c * 16 + w + 8 * u) * 8) * 512 + lr * 32 + lq * 8;
#pragma unroll
    for (int sp = 0; sp < 8; ++sp) agR[u][sp] = *(const uint4*)(ag + sp * 512);
  }
  u16 sraw[2][4];
  float xs[2][4];
#pragma unroll
  for (int u = 0; u < 2; ++u) {
    const size_t T = (size_t)c * CC + w + 8 * u;
    ushort4 pk;
#pragma unroll
    for (int r = 0; r < 4; ++r) {
      size_t idx = (T * 16 + lq * 4 + r) * 256 + d1b * 16 + lr;
      sraw[u][r] = st[idx];
      xs[u][r] = bf2f(tr[idx]);
      ((u16*)&pk)[r] = sraw[u][r];
    }
    *(ushort4*)(&StT[w + 8 * u][lr * RP + lq * 4]) = pk;
  }
  __syncthreads();  // StT ready

#pragma unroll
  for (int u = 0; u < 2; ++u) {
    f32x4 a1 = {0.f, 0.f, 0.f, 0.f}, a2 = {0.f, 0.f, 0.f, 0.f};
#pragma unroll
    for (int sp = 0; sp < 8; ++sp) {
      const int s0 = 2 * sp + (lq >> 1);
      bf16x8 xb = ldfrag(trT + ((size_t)(c * CC + s0) * 256 + d1b * 16 + lr) * 16 +
                         (lq & 1) * 8);
      bf16x8 sb = ldfrag(&StT[s0][lr * RP + (lq & 1) * 8]);
      a1 = mfma16(asfrag(agR[u][sp]), xb, a1);
      a2 = mfma16(asfrag(agR[u][sp]), sb, a2);
    }
    ushort4 py, pz;
#pragma unroll
    for (int r = 0; r < 4; ++r) {
      ((u16*)&py)[r] = f2bf(xs[u][r] - KAPPA * a1[r]);
      ((u16*)&pz)[r] = f2bf(bf2f(sraw[u][r]) - KAPPA * a2[r]);
    }
    *(ushort4*)(&YtL[w + 8 * u][lr * RP + lq * 4]) = py;
    *(ushort4*)(&ZtL[w + 8 * u][lr * RP + lq * 4]) = pz;
  }
  __syncthreads();  // Ytil/Ztil ready

  bf16x8 yf[8], zf[8];
#pragma unroll
  for (int sp = 0; sp < 8; ++sp) {
    yf[sp] = ldfrag(&YtL[2 * sp + (lq >> 1)][lr * RP + (lq & 1) * 8]);
    zf[sp] = ldfrag(&ZtL[2 * sp + (lq >> 1)][lr * RP + (lq & 1) * 8]);
  }
  const size_t base = (size_t)c * SLOT;
#pragma unroll
  for (int u = 0; u < 2; ++u) {
    const int d2b = w + 8 * u;
    f32x4 da = {0.f, 0.f, 0.f, 0.f}, qa = {0.f, 0.f, 0.f, 0.f};
#pragma unroll
    for (int sp = 0; sp < 8; ++sp) {
      bf16x8 xb = ldfrag(trT + ((size_t)(c * CC + 2 * sp + (lq >> 1)) * 256 +
                                d2b * 16 + lr) * 16 + (lq & 1) * 8);
      da = mfma16(yf[sp], xb, da);
      qa = mfma16(zf[sp], xb, qa);
    }
    ushort4 dpk;
#pragma unroll
    for (int r = 0; r < 4; ++r) {
      const u16 dv = f2bf(-KAPPA * da[r]);
      ((u16*)&dpk)[r] = dv;
      // Db normal: [d1][d2]
      Db[base + (size_t)(d1b * 16 + lq * 4 + r) * 256 + d2b * 16 + lr] = dv;
      // Q normal: [d1][d2]
      Qb[base + (size_t)(d1b * 16 + lq * 4 + r) * 256 + d2b * 16 + lr] =
          f2bf(KAPPA * qa[r]);
    }
    // Dt transposed: [d2][d1], contiguous in r
    *(ushort4*)(Dt + base + (size_t)(d2b * 16 + lr) * 256 + d1b * 16 + lq * 4) = dpk;
  }
}

// ---------------- Sklansky level: Q update (runs BEFORE kdt) ---------------
// Q_i'' = Q_j + Q_i + Q_j@D_i.  Reads read-only slot j + untouched Dt_i.
__global__ __launch_bounds__(512) void kq_kernel(
    const u16* __restrict__ Dt, u16* __restrict__ Qb, int lev) {
  const int qn = blockIdx.x >> 4, rb = blockIdx.x & 15;
  const int half = 1 << (lev - 1);
  const int blk = qn >> (lev - 1), win = qn & (half - 1);
  const int i = blk * half * 2 + half + win;
  const int j = blk * half * 2 + half - 1;
  u16* Qi = Qb + (size_t)i * SLOT;
  const u16* Qj = Qb + (size_t)j * SLOT;
  const u16* Dti = Dt + (size_t)i * SLOT;
  const int lane = threadIdx.x & 63, w = threadIdx.x >> 6;
  const int lr = lane & 15, lq = lane >> 4;
  bf16x8 aq[8];
#pragma unroll
  for (int kb = 0; kb < 8; ++kb)
    aq[kb] = ldfrag(Qj + (size_t)(rb * 16 + lr) * 256 + kb * 32 + lq * 8);
#pragma unroll
  for (int u = 0; u < 2; ++u) {
    const int cb = w + 8 * u;
    f32x4 acc = {0.f, 0.f, 0.f, 0.f};
#pragma unroll
    for (int kb = 0; kb < 8; ++kb) {
      bf16x8 bf = ldfrag(Dti + (size_t)(cb * 16 + lr) * 256 + kb * 32 + lq * 8);
      acc = mfma16(aq[kb], bf, acc);
    }
#pragma unroll
    for (int r = 0; r < 4; ++r) {
      size_t idx = (size_t)(rb * 16 + lq * 4 + r) * 256 + cb * 16 + lr;
      float v = acc[r] + bf2f(Qj[idx]) + bf2f(Qi[idx]);
      Qi[idx] = f2bf(v);
    }
  }
}

// ---------------- Sklansky level: Dt update (+ mirror into Db) -------------
// Dt_i'' = Dt_j + Dt_i + Dt_i@Dt_j.  B-frags now contiguous from Db_j
// (Db_j rows == Dt_j columns) -- replaces the old 128-scalar gather.
// Mirror-writes the new tile into Db_i so Db stays current for later levels.
__global__ __launch_bounds__(512) void kdt_kernel(
    u16* __restrict__ Dt, u16* __restrict__ Db, int lev) {
  const int qn = blockIdx.x >> 4, rb = blockIdx.x & 15;
  const int half = 1 << (lev - 1);
  const int blk = qn >> (lev - 1), win = qn & (half - 1);
  const int i = blk * half * 2 + half + win;
  const int j = blk * half * 2 + half - 1;
  u16* Dti = Dt + (size_t)i * SLOT;
  const u16* Dtj = Dt + (size_t)j * SLOT;
  u16* Dbi = Db + (size_t)i * SLOT;
  const u16* Dbj = Db + (size_t)j * SLOT;
  const int lane = threadIdx.x & 63, w = threadIdx.x >> 6;
  const int lr = lane & 15, lq = lane >> 4;
  bf16x8 ad[8];
#pragma unroll
  for (int kb = 0; kb < 8; ++kb)
    ad[kb] = ldfrag(Dti + (size_t)(rb * 16 + lr) * 256 + kb * 32 + lq * 8);
  float oldv[2][4];
#pragma unroll
  for (int u = 0; u < 2; ++u) {
    const int cb = w + 8 * u;
#pragma unroll
    for (int r = 0; r < 4; ++r) {
      size_t idx = (size_t)(rb * 16 + lq * 4 + r) * 256 + cb * 16 + lr;
      oldv[u][r] = bf2f(Dtj[idx]) + bf2f(Dti[idx]);
    }
  }
  __syncthreads();  // all reads of Dt_i rows complete before any wave stores
#pragma unroll
  for (int u = 0; u < 2; ++u) {
    const int cb = w + 8 * u;
    f32x4 acc = {0.f, 0.f, 0.f, 0.f};
#pragma unroll
    for (int kb = 0; kb < 8; ++kb) {
      bf16x8 bf = ldfrag(Dbj + (size_t)(cb * 16 + lr) * 256 + kb * 32 + lq * 8);
      acc = mfma16(ad[kb], bf, acc);
    }
    ushort4 mir;
#pragma unroll
    for (int r = 0; r < 4; ++r) {
      const u16 nv = f2bf(acc[r] + oldv[u][r]);
      ((u16*)&mir)[r] = nv;
      Dti[(size_t)(rb * 16 + lq * 4 + r) * 256 + cb * 16 + lr] = nv;
    }
    // mirror: Db_i[col][row], contiguous in r
    *(ushort4*)(Dbi + (size_t)(cb * 16 + lr) * 256 + rb * 16 + lq * 4) = mir;
  }
}

// ---------------- wstart: Wsb[c] = bf16(W0 + W0@Dex + Qex), once per chunk -
__global__ __launch_bounds__(512) void wstart_kernel(
    const float* __restrict__ Wttt, const u16* __restrict__ Dt,
    const u16* __restrict__ Qb, u16* __restrict__ Wsb) {
  const int c = blockIdx.x;           // 0..127
  const int tid = threadIdx.x;
  const int lane = tid & 63, w = tid >> 6;
  const int lr = lane & 15, lq = lane >> 4;
  if (c == 0) {
    for (int i = tid; i < SLOT / 4; i += 512) {
      float4 v = *(const float4*)(Wttt + (size_t)i * 4);
      ushort4 o;
      o.x = f2bf(v.x); o.y = f2bf(v.y); o.z = f2bf(v.z); o.w = f2bf(v.w);
      *(ushort4*)(Wsb + (size_t)i * 4) = o;
    }
    return;
  }
  const size_t ex = (size_t)(c - 1) * SLOT;
  u16* Wc = Wsb + (size_t)c * SLOT;
#pragma unroll
  for (int ui = 0; ui < 2; ++ui) {
    const int rb = w + 8 * ui;
    bf16x8 wf[8];
#pragma unroll
    for (int kb = 0; kb < 8; ++kb) {
      const float* wp = Wttt + (size_t)(rb * 16 + lr) * 256 + kb * 32 + lq * 8;
      float4 w0 = *(const float4*)(wp);
      float4 w1 = *(const float4*)(wp + 4);
      union { u16 s[8]; bf16x8 f; } cv;
      cv.s[0] = f2bf(w0.x); cv.s[1] = f2bf(w0.y);
      cv.s[2] = f2bf(w0.z); cv.s[3] = f2bf(w0.w);
      cv.s[4] = f2bf(w1.x); cv.s[5] = f2bf(w1.y);
      cv.s[6] = f2bf(w1.z); cv.s[7] = f2bf(w1.w);
      wf[kb] = cv.f;
    }
    for (int cb = 0; cb < 16; ++cb) {
      f32x4 acc = {0.f, 0.f, 0.f, 0.f};
#pragma unroll
      for (int kb = 0; kb < 8; ++kb) {
        bf16x8 bf = ldfrag(Dt + ex + (size_t)(cb * 16 + lr) * 256 + kb * 32 + lq * 8);
        acc = mfma16(wf[kb], bf, acc);
      }
#pragma unroll
      for (int r = 0; r < 4; ++r) {
        size_t idx = (size_t)(rb * 16 + lq * 4 + r) * 256 + cb * 16 + lr;
        float v = Wttt[idx] + acc[r] + bf2f(Qb[ex + idx]);
        Wc[idx] = f2bf(v);
      }
    }
  }
}

// ---------------- phase C: parallel per-chunk readout ----------------------
// Grid dim3(16,128): blockIdx.x = d1b, blockIdx.y = c.  W_start comes
// precomputed from Wsb (8 KB vector copy), then the verified chunk body:
// P1 -> P2' -> P4a with g-add.
__global__ __launch_bounds__(512) void phaseC_kernel(
    const u16* __restrict__ tr, const u16* __restrict__ st,
    const u16* __restrict__ AG, const u16* __restrict__ LbG,
    const u16* __restrict__ Wsb, float* __restrict__ out) {
  __shared__ u16 RpL[CC][16 * RP];
  __shared__ u16 DpL[CC][16 * RP];
  __shared__ u16 WbL[16][268];

  const int tid = threadIdx.x;
  const int lane = tid & 63;
  const int w = tid >> 6;
  const int d1b = blockIdx.x;
  const int c = blockIdx.y;
  const int lr = lane & 15;
  const int lq = lane >> 4;

  // ---- prologue: WbL = Wsb[c] rows d1b (vector copy) ----
  {
    const int row = tid >> 5, col = (tid & 31) * 8;
    *(uint4*)&WbL[row][col] =
        *(const uint4*)(Wsb + (size_t)c * SLOT + (size_t)(d1b * 16 + row) * 256 + col);
  }
  __syncthreads();

  // ---- prefetch AG frags for both t's ----
  uint4 agR[2][8];
#pragma unroll
  for (int u = 0; u < 2; ++u) {
    const u16* ag = AG + ((size_t)(c * 16 + w + 8 * u) * 8) * 512 + lr * 32 + lq * 8;
#pragma unroll
    for (int sp = 0; sp < 8; ++sp) agR[u][sp] = *(const uint4*)(ag + sp * 512);
  }
  // ---- P1 loads ----
  uint4 trR[2][8], stR[2][8];
  float sub[2][4];
#pragma unroll
  for (int u = 0; u < 2; ++u) {
    const size_t T = (size_t)c * CC + w + 8 * u;
    const u16* trt = tr + (T * 16 + lr) * 256 + lq * 8;
    const u16* stt = st + (T * 16 + lr) * 256 + lq * 8;
#pragma unroll
    for (int k = 0; k < 8; ++k) {
      trR[u][k] = *(const uint4*)(trt + k * 32);
      stR[u][k] = *(const uint4*)(stt + k * 32);
    }
#pragma unroll
    for (int r = 0; r < 4; ++r)
      sub[u][r] = bf2f(st[(T * 16 + lq * 4 + r) * 256 + d1b * 16 + lr]);
  }

  // ---- P1: rhs = tr@W^T - st ; q = st@W^T ----
  f32x4 rhsF[2], qF[2];
#pragma unroll
  for (int u = 0; u < 2; ++u) {
    f32x4 racc = {0.f, 0.f, 0.f, 0.f}, qacc = {0.f, 0.f, 0.f, 0.f};
#pragma unroll
    for (int k = 0; k < 8; ++k) {
      bf16x8 wb = ldfrag(&WbL[lr][k * 32 + lq * 8]);
      racc = mfma16(asfrag(trR[u][k]), wb, racc);
      qacc = mfma16(asfrag(stR[u][k]), wb, qacc);
    }
#pragma unroll
    for (int r = 0; r < 4; ++r) racc[r] -= sub[u][r];
    rhsF[u] = racc; qF[u] = qacc;
    ushort4 pk;
    pk.x = f2bf(racc.x); pk.y = f2bf(racc.y);
    pk.z = f2bf(racc.z); pk.w = f2bf(racc.w);
    *(ushort4*)(&RpL[w + 8 * u][lr * RP + lq * 4]) = pk;
  }
  __syncthreads();  // b1

  // ---- LbG frags ----
  uint4 lbR[2][8];
#pragma unroll
  for (int u = 0; u < 2; ++u) {
    const u16* lb = LbG + ((size_t)(c * 16 + w + 8 * u) * 8) * 512 + lr * 32 + lq * 8;
#pragma unroll
    for (int sp = 0; sp < 8; ++sp) lbR[u][sp] = *(const uint4*)(lb + sp * 512);
  }

  // ---- P2': z = A @ rhs ; Dp = -k*(rhs - k*z) ----
#pragma unroll
  for (int u = 0; u < 2; ++u) {
    f32x4 acc = {0.f, 0.f, 0.f, 0.f};
#pragma unroll
    for (int sp = 0; sp < 8; ++sp) {
      bf16x8 bf = ldfrag(&RpL[2 * sp + (lq >> 1)][lr * RP + (lq & 1) * 8]);
      acc = mfma16(asfrag(agR[u][sp]), bf, acc);
    }
    ushort4 pk;
#pragma unroll
    for (int r = 0; r < 4; ++r) {
      float dv = rhsF[u][r] - KAPPA * acc[r];
      ((u16*)&pk)[r] = f2bf(-KAPPA * dv);
    }
    *(ushort4*)(&DpL[w + 8 * u][lr * RP + lq * 4]) = pk;
  }
  __syncthreads();  // b2

  // ---- P4: Out = g + q + Lb @ Dp ----
  float gp[2][4];
#pragma unroll
  for (int u = 0; u < 2; ++u) {
    const size_t T = (size_t)c * CC + w + 8 * u;
#pragma unroll
    for (int r = 0; r < 4; ++r)
      gp[u][r] = out[((size_t)(lq * 4 + r) * SS + T) * SD + d1b * 16 + lr];
  }
#pragma unroll
  for (int u = 0; u < 2; ++u) {
    const size_t T = (size_t)c * CC + w + 8 * u;
    f32x4 acc = qF[u];
#pragma unroll
    for (int sp = 0; sp < 8; ++sp) {
      bf16x8 bf = ldfrag(&DpL[2 * sp + (lq >> 1)][lr * RP + (lq & 1) * 8]);
      acc = mfma16(asfrag(lbR[u][sp]), bf, acc);
    }
#pragma unroll
    for (int r = 0; r < 4; ++r) {
      size_t oi = ((size_t)(lq * 4 + r) * SS + T) * SD + d1b * 16 + lr;
      out[oi] = acc[r] + gp[u][r];
    }
  }
}

extern "C" void kernel_launch(void* const* d_in, const int* in_sizes, int n_in,
                              void* d_out, int out_size, void* d_ws, size_t ws_size,
                              hipStream_t stream) {
  const float* x     = (const float*)d_in[0];
  const float* noise = (const float*)d_in[1];
  const float* a1    = (const float*)d_in[2];
  const float* a2    = (const float*)d_in[3];
  const float* Wttt  = (const float*)d_in[4];
  const float* Wproj = (const float*)d_in[5];
  const float* ffa   = (const float*)d_in[6];
  const float* ffb   = (const float*)d_in[7];
  const float* ffg   = (const float*)d_in[8];
  const float* ffe   = (const float*)d_in[9];
  float* out = (float*)d_out;

  const size_t N = (size_t)SB * SS * SD;   // 8388608 elements
  u16* tr  = (u16*)d_ws;
  u16* st  = tr + N;
  u16* trT = st + N;
  u16* AG  = trT + N;
  u16* LbG = AG + N;
  u16* Dt  = LbG + N;   // 128 slots x 65536 bf16 (transposed D)
  u16* Qb  = Dt + N;    // 128 slots x 65536 bf16 (Q)
  u16* Db  = Qb + N;    // 128 slots x 65536 bf16 (normal D)
  u16* Wsb = trT;       // alias: trT dead after phaseA; 128 x 65536 bf16
  // total ws usage = 8N * 2B ~ 134.2 MB

  prep_kernel<<<8192, 256, 0, stream>>>(x, noise, a1, tr, st, trT);
  gram2ff_kernel<<<4096, 256, 0, stream>>>(tr, st, AG, LbG,
                                           x, a2, Wproj, ffa, ffb, ffg, ffe, out);
  phaseA_kernel<<<dim3(16, 128), 512, 0, stream>>>(tr, st, trT, AG, Dt, Db, Qb);
  for (int lev = 1; lev <= 7; ++lev) {
    kq_kernel<<<1024, 512, 0, stream>>>(Dt, Qb, lev);
    kdt_kernel<<<1024, 512, 0, stream>>>(Dt, Db, lev);
  }
  wstart_kernel<<<128, 512, 0, stream>>>(Wttt, Dt, Qb, Wsb);
  phaseC_kernel<<<dim3(16, 128), 512, 0, stream>>>(tr, st, AG, LbG, Wsb, out);
}

// Round 8
// 894.439 us; speedup vs baseline: 1.0280x; 1.0280x over previous
//
#include <hip/hip_runtime.h>

typedef unsigned short u16;
typedef unsigned int u32;
typedef __attribute__((ext_vector_type(8))) short bf16x8;
typedef __attribute__((ext_vector_type(4))) float f32x4;

#define SB 16
#define SS 2048
#define SD 256
#define CC 16            // chunk length
#define NCH (SS / CC)    // 128 chunks
#define KAPPA 4.8828125e-6f   // 0.01 * 2/(16*256)
#define RP 24            // u16 pitch of transposed 16x16 publish tiles
#define SLOT 65536       // elements per [256,256] transfer slot

__device__ __forceinline__ u16 f2bf(float f) {
  u32 u = __float_as_uint(f);
  u = (u + 0x7FFFu + ((u >> 16) & 1u)) >> 16;
  return (u16)u;
}
__device__ __forceinline__ float bf2f(u16 u) { return __uint_as_float((u32)u << 16); }

__device__ __forceinline__ bf16x8 ldfrag(const u16* p) {
  union { uint4 u; bf16x8 f; } cv;
  cv.u = *(const uint4*)p;
  return cv.f;
}
__device__ __forceinline__ bf16x8 asfrag(uint4 q) {
  union { uint4 u; bf16x8 f; } cv;
  cv.u = q;
  return cv.f;
}
__device__ __forceinline__ f32x4 mfma16(bf16x8 a, bf16x8 b, f32x4 c) {
  return __builtin_amdgcn_mfma_f32_16x16x32_bf16(a, b, c, 0, 0, 0);
}

// ---------------- prep: train/state/trainT + ff's v = tanh(a2*x) hi/lo -----
__global__ __launch_bounds__(256) void prep_kernel(
    const float* __restrict__ x, const float* __restrict__ noise,
    const float* __restrict__ a1, const float* __restrict__ a2,
    u16* __restrict__ train, u16* __restrict__ state, u16* __restrict__ trainT,
    u16* __restrict__ vh, u16* __restrict__ vl) {
  size_t i4 = (size_t)blockIdx.x * 256 + threadIdx.x;
  size_t base = i4 * 4;
  int d = (int)(base & 255);
  int t = (int)((base >> 8) & 2047);
  int b = (int)(base >> 19);
  float4 xv = *(const float4*)(x + base);
  float4 nv = *(const float4*)(noise + base);
  float4 av = *(const float4*)(a1 + d);
  float4 a2v = *(const float4*)(a2 + d);
  float m0 = tanhf(av.x * xv.x);
  float m1 = tanhf(av.y * xv.y);
  float m2 = tanhf(av.z * xv.z);
  float m3 = tanhf(av.w * xv.w);
  size_t dst = ((size_t)t * SB + b) * SD + d;
  ushort4 tr, st;
  tr.x = f2bf(m0 + nv.x); tr.y = f2bf(m1 + nv.y);
  tr.z = f2bf(m2 + nv.z); tr.w = f2bf(m3 + nv.w);
  st.x = f2bf(m0); st.y = f2bf(m1); st.z = f2bf(m2); st.w = f2bf(m3);
  *(ushort4*)(train + dst) = tr;
  *(ushort4*)(state + dst) = st;
  size_t tb = ((size_t)t * SD + d) * SB + b;   // trainT[t][d][b]
  trainT[tb + 0 * SB] = tr.x;
  trainT[tb + 1 * SB] = tr.y;
  trainT[tb + 2 * SB] = tr.z;
  trainT[tb + 3 * SB] = tr.w;
  // ff path: v = tanh(a2*x), split hi/lo bf16, row-major [b*S+t][d] == base
  float v0 = tanhf(a2v.x * xv.x);
  float v1 = tanhf(a2v.y * xv.y);
  float v2 = tanhf(a2v.z * xv.z);
  float v3 = tanhf(a2v.w * xv.w);
  ushort4 h, l;
  h.x = f2bf(v0); l.x = f2bf(v0 - bf2f(h.x));
  h.y = f2bf(v1); l.y = f2bf(v1 - bf2f(h.y));
  h.z = f2bf(v2); l.z = f2bf(v2 - bf2f(h.z));
  h.w = f2bf(v3); l.w = f2bf(v3 - bf2f(h.w));
  *(ushort4*)(vh + base) = h;
  *(ushort4*)(vl + base) = l;
}

// ---------------- wsplit: Wp fp32 -> bf16 hi/lo ----------------------------
__global__ __launch_bounds__(256) void wsplit_kernel(
    const float* __restrict__ Wp, u16* __restrict__ Wph, u16* __restrict__ Wpl) {
  size_t i = ((size_t)blockIdx.x * 256 + threadIdx.x) * 4;
  float4 v = *(const float4*)(Wp + i);
  ushort4 h, l;
  h.x = f2bf(v.x); l.x = f2bf(v.x - bf2f(h.x));
  h.y = f2bf(v.y); l.y = f2bf(v.y - bf2f(h.y));
  h.z = f2bf(v.z); l.z = f2bf(v.z - bf2f(h.z));
  h.w = f2bf(v.w); l.w = f2bf(v.w - bf2f(h.w));
  *(ushort4*)(Wph + i) = h;
  *(ushort4*)(Wpl + i) = l;
}

// ---------------- fused: gram2 (blocks 0..2047) || ff (blocks 2048..4095) --
// ff is now a split-bf16 MFMA GEMM: acc = vh@Wh + vl@Wh + vh@Wl (~fp32),
// epilogue u-factor (erf/sin) from reconstructed v.  No LDS, no tanh.
__global__ __launch_bounds__(256) void gram2ff_kernel(
    const u16* __restrict__ tr, const u16* __restrict__ st,
    u16* __restrict__ AG, u16* __restrict__ LbG,
    const u16* __restrict__ vh, const u16* __restrict__ vl,
    const u16* __restrict__ Wph, const u16* __restrict__ Wpl,
    const float* __restrict__ ffa, const float* __restrict__ ffb,
    const float* __restrict__ ffg_, const float* __restrict__ ffe_,
    float* __restrict__ out) {
  const int tid = threadIdx.x;

  if (blockIdx.x < 2048) {
    const int cb = blockIdx.x;        // c*16 + t
    const int c = cb >> 4, t = cb & 15;
    const int lane = tid & 63, wv = tid >> 6;
    const int lr = lane & 15, lq = lane >> 4;
    const size_t Tt = (size_t)cb;
    bf16x8 trF[8], stF[8];
#pragma unroll
    for (int k = 0; k < 8; ++k) {
      trF[k] = ldfrag(tr + (Tt * 16 + lr) * 256 + k * 32 + lq * 8);
      stF[k] = ldfrag(st + (Tt * 16 + lr) * 256 + k * 32 + lq * 8);
    }
    for (int ii = 0; ii < 2; ++ii) {
      const int sp = wv + ii * 4;
      u16* dA = AG + ((size_t)cb * 8 + sp) * 512;
      u16* dL = LbG + ((size_t)cb * 8 + sp) * 512;
#pragma unroll
      for (int h = 0; h < 2; ++h) {
        const int s = 2 * sp + h;
        f32x4 accA = {0.f, 0.f, 0.f, 0.f}, accL = {0.f, 0.f, 0.f, 0.f};
        if (s <= t) {
          const u16* bsrc = tr + ((size_t)(c * 16 + s) * 16 + lr) * 256 + lq * 8;
#pragma unroll
          for (int k = 0; k < 8; ++k) {
            bf16x8 bk = ldfrag(bsrc + k * 32);
            if (s < t) accA = mfma16(trF[k], bk, accA);
            accL = mfma16(stF[k], bk, accL);
          }
        }
#pragma unroll
        for (int r = 0; r < 4; ++r) {
          int idx = (lq * 4 + r) * 32 + h * 16 + lr;
          dA[idx] = (s < t) ? f2bf(accA[r]) : (u16)0;
          dL[idx] = (s <= t) ? f2bf(accL[r]) : (u16)0;
        }
      }
    }
    return;
  }

  // ---------------- ff body: out = u .* (v @ Wp^T) via split-bf16 MFMA ----
  const int fb = blockIdx.x - 2048;
  // XCD affinity: 4 gn0-blocks of one gm0 share blockIdx mod 8 (A-row reuse)
  const int gm0 = ((fb & 7) + 8 * (fb >> 5)) * 64;
  const int gn0 = ((fb >> 3) & 3) * 64;
  const int lane = tid & 63, w = tid >> 6;   // 4 waves, 16 rows each
  const int lr = lane & 15, lq = lane >> 4;

  bf16x8 ah[8], al[8];
  {
    const u16* vhp = vh + (size_t)(gm0 + w * 16 + lr) * 256 + lq * 8;
    const u16* vlp = vl + (size_t)(gm0 + w * 16 + lr) * 256 + lq * 8;
#pragma unroll
    for (int kb = 0; kb < 8; ++kb) {
      ah[kb] = ldfrag(vhp + kb * 32);
      al[kb] = ldfrag(vlp + kb * 32);
    }
  }
  const float ga = ffg_[0], et = ffe_[0];
#pragma unroll
  for (int cb = 0; cb < 4; ++cb) {
    const u16* bhp = Wph + (size_t)(gn0 + cb * 16 + lr) * 256 + lq * 8;
    const u16* blp = Wpl + (size_t)(gn0 + cb * 16 + lr) * 256 + lq * 8;
    f32x4 acc = {0.f, 0.f, 0.f, 0.f};
#pragma unroll
    for (int kb = 0; kb < 8; ++kb) {
      bf16x8 bh = ldfrag(bhp + kb * 32);
      bf16x8 bl = ldfrag(blp + kb * 32);
      acc = mfma16(ah[kb], bh, acc);
      acc = mfma16(al[kb], bh, acc);
      acc = mfma16(ah[kb], bl, acc);
    }
#pragma unroll
    for (int r = 0; r < 4; ++r) {
      const int row = gm0 + w * 16 + lq * 4 + r;
      const int col = gn0 + cb * 16 + lr;
      const size_t vi = (size_t)row * 256 + col;
      float v = bf2f(vh[vi]) + bf2f(vl[vi]);
      float z = ffa[col] * v;
      float gelu = 0.5f * z * (1.0f + erff(z * 0.70710678118654752f));
      float u = ga * gelu + et * sinf(ffb[col] * v);
      out[vi] = u * acc[r];
    }
  }
}

// ---------------- phase A: per-chunk transfer (Dt, Db both orientations) ---
// Grid 2048 (1D, XCD affinity: 16 d1b of a chunk share blockIdx mod 8).
__global__ __launch_bounds__(512) void phaseA_kernel(
    const u16* __restrict__ tr, const u16* __restrict__ st,
    const u16* __restrict__ trT, const u16* __restrict__ AG,
    u16* __restrict__ Dt, u16* __restrict__ Db, u16* __restrict__ Qb) {
  __shared__ u16 StT[CC][16 * RP];
  __shared__ u16 YtL[CC][16 * RP];
  __shared__ u16 ZtL[CC][16 * RP];
  const int tid = threadIdx.x;
  const int lane = tid & 63;
  const int w = tid >> 6;
  const int id = blockIdx.x;
  const int c = (id & 7) + 8 * (id >> 7);
  const int d1b = (id >> 3) & 15;
  const int lr = lane & 15;
  const int lq = lane >> 4;

  uint4 agR[2][8];
#pragma unroll
  for (int u = 0; u < 2; ++u) {
    const u16* ag = AG + ((size_t)(c * 16 + w + 8 * u) * 8) * 512 + lr * 32 + lq * 8;
#pragma unroll
    for (int sp = 0; sp < 8; ++sp) agR[u][sp] = *(const uint4*)(ag + sp * 512);
  }
  u16 sraw[2][4];
  float xs[2][4];
#pragma unroll
  for (int u = 0; u < 2; ++u) {
    const size_t T = (size_t)c * CC + w + 8 * u;
    ushort4 pk;
#pragma unroll
    for (int r = 0; r < 4; ++r) {
      size_t idx = (T * 16 + lq * 4 + r) * 256 + d1b * 16 + lr;
      sraw[u][r] = st[idx];
      xs[u][r] = bf2f(tr[idx]);
      ((u16*)&pk)[r] = sraw[u][r];
    }
    *(ushort4*)(&StT[w + 8 * u][lr * RP + lq * 4]) = pk;
  }
  __syncthreads();  // StT ready

#pragma unroll
  for (int u = 0; u < 2; ++u) {
    f32x4 a1 = {0.f, 0.f, 0.f, 0.f}, a2 = {0.f, 0.f, 0.f, 0.f};
#pragma unroll
    for (int sp = 0; sp < 8; ++sp) {
      const int s0 = 2 * sp + (lq >> 1);
      bf16x8 xb = ldfrag(trT + ((size_t)(c * CC + s0) * 256 + d1b * 16 + lr) * 16 +
                         (lq & 1) * 8);
      bf16x8 sb = ldfrag(&StT[s0][lr * RP + (lq & 1) * 8]);
      a1 = mfma16(asfrag(agR[u][sp]), xb, a1);
      a2 = mfma16(asfrag(agR[u][sp]), sb, a2);
    }
    ushort4 py, pz;
#pragma unroll
    for (int r = 0; r < 4; ++r) {
      ((u16*)&py)[r] = f2bf(xs[u][r] - KAPPA * a1[r]);
      ((u16*)&pz)[r] = f2bf(bf2f(sraw[u][r]) - KAPPA * a2[r]);
    }
    *(ushort4*)(&YtL[w + 8 * u][lr * RP + lq * 4]) = py;
    *(ushort4*)(&ZtL[w + 8 * u][lr * RP + lq * 4]) = pz;
  }
  __syncthreads();  // Ytil/Ztil ready

  bf16x8 yf[8], zf[8];
#pragma unroll
  for (int sp = 0; sp < 8; ++sp) {
    yf[sp] = ldfrag(&YtL[2 * sp + (lq >> 1)][lr * RP + (lq & 1) * 8]);
    zf[sp] = ldfrag(&ZtL[2 * sp + (lq >> 1)][lr * RP + (lq & 1) * 8]);
  }
  const size_t base = (size_t)c * SLOT;
#pragma unroll
  for (int u = 0; u < 2; ++u) {
    const int d2b = w + 8 * u;
    f32x4 da = {0.f, 0.f, 0.f, 0.f}, qa = {0.f, 0.f, 0.f, 0.f};
#pragma unroll
    for (int sp = 0; sp < 8; ++sp) {
      bf16x8 xb = ldfrag(trT + ((size_t)(c * CC + 2 * sp + (lq >> 1)) * 256 +
                                d2b * 16 + lr) * 16 + (lq & 1) * 8);
      da = mfma16(yf[sp], xb, da);
      qa = mfma16(zf[sp], xb, qa);
    }
    ushort4 dpk;
#pragma unroll
    for (int r = 0; r < 4; ++r) {
      const u16 dv = f2bf(-KAPPA * da[r]);
      ((u16*)&dpk)[r] = dv;
      Db[base + (size_t)(d1b * 16 + lq * 4 + r) * 256 + d2b * 16 + lr] = dv;
      Qb[base + (size_t)(d1b * 16 + lq * 4 + r) * 256 + d2b * 16 + lr] =
          f2bf(KAPPA * qa[r]);
    }
    *(ushort4*)(Dt + base + (size_t)(d2b * 16 + lr) * 256 + d1b * 16 + lq * 4) = dpk;
  }
}

// ---------------- Sklansky level: Q update (runs BEFORE kdt) ---------------
// Grid 1024 (1D, XCD affinity: 16 row-blocks of a slot share blockIdx mod 8).
__global__ __launch_bounds__(512) void kq_kernel(
    const u16* __restrict__ Dt, u16* __restrict__ Qb, int lev) {
  const int id = blockIdx.x;
  const int qn = (id & 7) + 8 * (id >> 7);
  const int rb = (id >> 3) & 15;
  const int half = 1 << (lev - 1);
  const int blk = qn >> (lev - 1), win = qn & (half - 1);
  const int i = blk * half * 2 + half + win;
  const int j = blk * half * 2 + half - 1;
  u16* Qi = Qb + (size_t)i * SLOT;
  const u16* Qj = Qb + (size_t)j * SLOT;
  const u16* Dti = Dt + (size_t)i * SLOT;
  const int lane = threadIdx.x & 63, w = threadIdx.x >> 6;
  const int lr = lane & 15, lq = lane >> 4;
  bf16x8 aq[8];
#pragma unroll
  for (int kb = 0; kb < 8; ++kb)
    aq[kb] = ldfrag(Qj + (size_t)(rb * 16 + lr) * 256 + kb * 32 + lq * 8);
#pragma unroll
  for (int u = 0; u < 2; ++u) {
    const int cb = w + 8 * u;
    f32x4 acc = {0.f, 0.f, 0.f, 0.f};
#pragma unroll
    for (int kb = 0; kb < 8; ++kb) {
      bf16x8 bf = ldfrag(Dti + (size_t)(cb * 16 + lr) * 256 + kb * 32 + lq * 8);
      acc = mfma16(aq[kb], bf, acc);
    }
#pragma unroll
    for (int r = 0; r < 4; ++r) {
      size_t idx = (size_t)(rb * 16 + lq * 4 + r) * 256 + cb * 16 + lr;
      float v = acc[r] + bf2f(Qj[idx]) + bf2f(Qi[idx]);
      Qi[idx] = f2bf(v);
    }
  }
}

// ---------------- Sklansky level: Dt update (+ mirror into Db) -------------
__global__ __launch_bounds__(512) void kdt_kernel(
    u16* __restrict__ Dt, u16* __restrict__ Db, int lev) {
  const int id = blockIdx.x;
  const int qn = (id & 7) + 8 * (id >> 7);
  const int rb = (id >> 3) & 15;
  const int half = 1 << (lev - 1);
  const int blk = qn >> (lev - 1), win = qn & (half - 1);
  const int i = blk * half * 2 + half + win;
  const int j = blk * half * 2 + half - 1;
  u16* Dti = Dt + (size_t)i * SLOT;
  const u16* Dtj = Dt + (size_t)j * SLOT;
  u16* Dbi = Db + (size_t)i * SLOT;
  const u16* Dbj = Db + (size_t)j * SLOT;
  const int lane = threadIdx.x & 63, w = threadIdx.x >> 6;
  const int lr = lane & 15, lq = lane >> 4;
  bf16x8 ad[8];
#pragma unroll
  for (int kb = 0; kb < 8; ++kb)
    ad[kb] = ldfrag(Dti + (size_t)(rb * 16 + lr) * 256 + kb * 32 + lq * 8);
  float oldv[2][4];
#pragma unroll
  for (int u = 0; u < 2; ++u) {
    const int cb = w + 8 * u;
#pragma unroll
    for (int r = 0; r < 4; ++r) {
      size_t idx = (size_t)(rb * 16 + lq * 4 + r) * 256 + cb * 16 + lr;
      oldv[u][r] = bf2f(Dtj[idx]) + bf2f(Dti[idx]);
    }
  }
  __syncthreads();  // all reads of Dt_i rows complete before any wave stores
#pragma unroll
  for (int u = 0; u < 2; ++u) {
    const int cb = w + 8 * u;
    f32x4 acc = {0.f, 0.f, 0.f, 0.f};
#pragma unroll
    for (int kb = 0; kb < 8; ++kb) {
      bf16x8 bf = ldfrag(Dbj + (size_t)(cb * 16 + lr) * 256 + kb * 32 + lq * 8);
      acc = mfma16(ad[kb], bf, acc);
    }
    ushort4 mir;
#pragma unroll
    for (int r = 0; r < 4; ++r) {
      const u16 nv = f2bf(acc[r] + oldv[u][r]);
      ((u16*)&mir)[r] = nv;
      Dti[(size_t)(rb * 16 + lq * 4 + r) * 256 + cb * 16 + lr] = nv;
    }
    *(ushort4*)(Dbi + (size_t)(cb * 16 + lr) * 256 + rb * 16 + lq * 4) = mir;
  }
}

// ---------------- wstart: Wsb[c] = bf16(W0 + W0@Dex + Qex), once per chunk -
__global__ __launch_bounds__(512) void wstart_kernel(
    const float* __restrict__ Wttt, const u16* __restrict__ Dt,
    const u16* __restrict__ Qb, u16* __restrict__ Wsb) {
  const int c = blockIdx.x;           // 0..127
  const int tid = threadIdx.x;
  const int lane = tid & 63, w = tid >> 6;
  const int lr = lane & 15, lq = lane >> 4;
  if (c == 0) {
    for (int i = tid; i < SLOT / 4; i += 512) {
      float4 v = *(const float4*)(Wttt + (size_t)i * 4);
      ushort4 o;
      o.x = f2bf(v.x); o.y = f2bf(v.y); o.z = f2bf(v.z); o.w = f2bf(v.w);
      *(ushort4*)(Wsb + (size_t)i * 4) = o;
    }
    return;
  }
  const size_t ex = (size_t)(c - 1) * SLOT;
  u16* Wc = Wsb + (size_t)c * SLOT;
#pragma unroll
  for (int ui = 0; ui < 2; ++ui) {
    const int rb = w + 8 * ui;
    bf16x8 wf[8];
#pragma unroll
    for (int kb = 0; kb < 8; ++kb) {
      const float* wp = Wttt + (size_t)(rb * 16 + lr) * 256 + kb * 32 + lq * 8;
      float4 w0 = *(const float4*)(wp);
      float4 w1 = *(const float4*)(wp + 4);
      union { u16 s[8]; bf16x8 f; } cv;
      cv.s[0] = f2bf(w0.x); cv.s[1] = f2bf(w0.y);
      cv.s[2] = f2bf(w0.z); cv.s[3] = f2bf(w0.w);
      cv.s[4] = f2bf(w1.x); cv.s[5] = f2bf(w1.y);
      cv.s[6] = f2bf(w1.z); cv.s[7] = f2bf(w1.w);
      wf[kb] = cv.f;
    }
    for (int cb = 0; cb < 16; ++cb) {
      f32x4 acc = {0.f, 0.f, 0.f, 0.f};
#pragma unroll
      for (int kb = 0; kb < 8; ++kb) {
        bf16x8 bf = ldfrag(Dt + ex + (size_t)(cb * 16 + lr) * 256 + kb * 32 + lq * 8);
        acc = mfma16(wf[kb], bf, acc);
      }
#pragma unroll
      for (int r = 0; r < 4; ++r) {
        size_t idx = (size_t)(rb * 16 + lq * 4 + r) * 256 + cb * 16 + lr;
        float v = Wttt[idx] + acc[r] + bf2f(Qb[ex + idx]);
        Wc[idx] = f2bf(v);
      }
    }
  }
}

// ---------------- phase C: parallel per-chunk readout ----------------------
// Grid 2048 (1D, XCD affinity by chunk).  W_start from Wsb, then the
// verified chunk body: P1 -> P2' -> P4a with g-add.
__global__ __launch_bounds__(512) void phaseC_kernel(
    const u16* __restrict__ tr, const u16* __restrict__ st,
    const u16* __restrict__ AG, const u16* __restrict__ LbG,
    const u16* __restrict__ Wsb, float* __restrict__ out) {
  __shared__ u16 RpL[CC][16 * RP];
  __shared__ u16 DpL[CC][16 * RP];
  __shared__ u16 WbL[16][268];

  const int tid = threadIdx.x;
  const int lane = tid & 63;
  const int w = tid >> 6;
  const int id = blockIdx.x;
  const int c = (id & 7) + 8 * (id >> 7);
  const int d1b = (id >> 3) & 15;
  const int lr = lane & 15;
  const int lq = lane >> 4;

  {
    const int row = tid >> 5, col = (tid & 31) * 8;
    *(uint4*)&WbL[row][col] =
        *(const uint4*)(Wsb + (size_t)c * SLOT + (size_t)(d1b * 16 + row) * 256 + col);
  }
  __syncthreads();

  uint4 agR[2][8];
#pragma unroll
  for (int u = 0; u < 2; ++u) {
    const u16* ag = AG + ((size_t)(c * 16 + w + 8 * u) * 8) * 512 + lr * 32 + lq * 8;
#pragma unroll
    for (int sp = 0; sp < 8; ++sp) agR[u][sp] = *(const uint4*)(ag + sp * 512);
  }
  uint4 trR[2][8], stR[2][8];
  float sub[2][4];
#pragma unroll
  for (int u = 0; u < 2; ++u) {
    const size_t T = (size_t)c * CC + w + 8 * u;
    const u16* trt = tr + (T * 16 + lr) * 256 + lq * 8;
    const u16* stt = st + (T * 16 + lr) * 256 + lq * 8;
#pragma unroll
    for (int k = 0; k < 8; ++k) {
      trR[u][k] = *(const uint4*)(trt + k * 32);
      stR[u][k] = *(const uint4*)(stt + k * 32);
    }
#pragma unroll
    for (int r = 0; r < 4; ++r)
      sub[u][r] = bf2f(st[(T * 16 + lq * 4 + r) * 256 + d1b * 16 + lr]);
  }

  f32x4 rhsF[2], qF[2];
#pragma unroll
  for (int u = 0; u < 2; ++u) {
    f32x4 racc = {0.f, 0.f, 0.f, 0.f}, qacc = {0.f, 0.f, 0.f, 0.f};
#pragma unroll
    for (int k = 0; k < 8; ++k) {
      bf16x8 wb = ldfrag(&WbL[lr][k * 32 + lq * 8]);
      racc = mfma16(asfrag(trR[u][k]), wb, racc);
      qacc = mfma16(asfrag(stR[u][k]), wb, qacc);
    }
#pragma unroll
    for (int r = 0; r < 4; ++r) racc[r] -= sub[u][r];
    rhsF[u] = racc; qF[u] = qacc;
    ushort4 pk;
    pk.x = f2bf(racc.x); pk.y = f2bf(racc.y);
    pk.z = f2bf(racc.z); pk.w = f2bf(racc.w);
    *(ushort4*)(&RpL[w + 8 * u][lr * RP + lq * 4]) = pk;
  }
  __syncthreads();  // b1

  uint4 lbR[2][8];
#pragma unroll
  for (int u = 0; u < 2; ++u) {
    const u16* lb = LbG + ((size_t)(c * 16 + w + 8 * u) * 8) * 512 + lr * 32 + lq * 8;
#pragma unroll
    for (int sp = 0; sp < 8; ++sp) lbR[u][sp] = *(const uint4*)(lb + sp * 512);
  }

#pragma unroll
  for (int u = 0; u < 2; ++u) {
    f32x4 acc = {0.f, 0.f, 0.f, 0.f};
#pragma unroll
    for (int sp = 0; sp < 8; ++sp) {
      bf16x8 bf = ldfrag(&RpL[2 * sp + (lq >> 1)][lr * RP + (lq & 1) * 8]);
      acc = mfma16(asfrag(agR[u][sp]), bf, acc);
    }
    ushort4 pk;
#pragma unroll
    for (int r = 0; r < 4; ++r) {
      float dv = rhsF[u][r] - KAPPA * acc[r];
      ((u16*)&pk)[r] = f2bf(-KAPPA * dv);
    }
    *(ushort4*)(&DpL[w + 8 * u][lr * RP + lq * 4]) = pk;
  }
  __syncthreads();  // b2

  float gp[2][4];
#pragma unroll
  for (int u = 0; u < 2; ++u) {
    const size_t T = (size_t)c * CC + w + 8 * u;
#pragma unroll
    for (int r = 0; r < 4; ++r)
      gp[u][r] = out[((size_t)(lq * 4 + r) * SS + T) * SD + d1b * 16 + lr];
  }
#pragma unroll
  for (int u = 0; u < 2; ++u) {
    const size_t T = (size_t)c * CC + w + 8 * u;
    f32x4 acc = qF[u];
#pragma unroll
    for (int sp = 0; sp < 8; ++sp) {
      bf16x8 bf = ldfrag(&DpL[2 * sp + (lq >> 1)][lr * RP + (lq & 1) * 8]);
      acc = mfma16(asfrag(lbR[u][sp]), bf, acc);
    }
#pragma unroll
    for (int r = 0; r < 4; ++r) {
      size_t oi = ((size_t)(lq * 4 + r) * SS + T) * SD + d1b * 16 + lr;
      out[oi] = acc[r] + gp[u][r];
    }
  }
}

extern "C" void kernel_launch(void* const* d_in, const int* in_sizes, int n_in,
                              void* d_out, int out_size, void* d_ws, size_t ws_size,
                              hipStream_t stream) {
  const float* x     = (const float*)d_in[0];
  const float* noise = (const float*)d_in[1];
  const float* a1    = (const float*)d_in[2];
  const float* a2    = (const float*)d_in[3];
  const float* Wttt  = (const float*)d_in[4];
  const float* Wproj = (const float*)d_in[5];
  const float* ffa   = (const float*)d_in[6];
  const float* ffb   = (const float*)d_in[7];
  const float* ffg   = (const float*)d_in[8];
  const float* ffe   = (const float*)d_in[9];
  float* out = (float*)d_out;

  const size_t N = (size_t)SB * SS * SD;   // 8388608 elements
  u16* tr  = (u16*)d_ws;
  u16* st  = tr + N;
  u16* trT = st + N;
  u16* AG  = trT + N;
  u16* LbG = AG + N;
  u16* Dt  = LbG + N;   // 128 slots x 65536 bf16 (transposed D)
  u16* Qb  = Dt + N;    // 128 slots x 65536 bf16 (Q)
  u16* Db  = Qb + N;    // 128 slots x 65536 bf16 (normal D)
  u16* Wsb = trT;       // alias: trT dead after phaseA
  // ff temporaries alias the transfer buffers (dead until phaseA):
  u16* vhB = Dt;        // v hi, N u16
  u16* vlB = Qb;        // v lo, N u16
  u16* Wph = Db;        // Wp hi, 65536 u16
  u16* Wpl = Db + SLOT; // Wp lo, 65536 u16
  // total ws usage = 8N * 2B ~ 134.2 MB

  prep_kernel<<<8192, 256, 0, stream>>>(x, noise, a1, a2, tr, st, trT, vhB, vlB);
  wsplit_kernel<<<64, 256, 0, stream>>>(Wproj, Wph, Wpl);
  gram2ff_kernel<<<4096, 256, 0, stream>>>(tr, st, AG, LbG, vhB, vlB, Wph, Wpl,
                                           ffa, ffb, ffg, ffe, out);
  phaseA_kernel<<<2048, 512, 0, stream>>>(tr, st, trT, AG, Dt, Db, Qb);
  for (int lev = 1; lev <= 7; ++lev) {
    kq_kernel<<<1024, 512, 0, stream>>>(Dt, Qb, lev);
    kdt_kernel<<<1024, 512, 0, stream>>>(Dt, Db, lev);
  }
  wstart_kernel<<<128, 512, 0, stream>>>(Wttt, Dt, Qb, Wsb);
  phaseC_kernel<<<2048, 512, 0, stream>>>(tr, st, AG, LbG, Wsb, out);
}